// Round 11
// baseline (490.214 us; speedup 1.0000x reference)
//
#include <hip/hip_runtime.h>
#include <cstdint>

#define BN 2
#define HN 16
#define NN 2048
#define DD 64
#define KT 64
#define NT (NN / KT)     // 32 tiles
#define LDP 72           // bf16 LDS row stride (fallback kernel)
#define LDH 36           // u32 words per Pbh row
#define KVELEMS ((size_t)BN * HN * NN * DD)   // 4,194,304 bf16 elems per region

typedef __attribute__((ext_vector_type(8))) short short8;
typedef __attribute__((ext_vector_type(2))) uint32_t uint2v;
typedef __attribute__((ext_vector_type(4))) uint32_t uint4v;
typedef __attribute__((ext_vector_type(4))) float float4v;

// packed f32->bf16 (RTNE), 2 elems / instr
static __device__ __forceinline__ uint32_t cvt_pk_bf16(float a, float b){
    uint32_t r;
    asm("v_cvt_pk_bf16_f32 %0, %1, %2" : "=v"(r) : "v"(a), "v"(b));
    return r;
}
static __device__ __forceinline__ unsigned short f2bf1(float a){
    return (unsigned short)(cvt_pk_bf16(a, a) & 0xffffu);
}
static __device__ __forceinline__ short8 pack8(float4v f0, float4v f1){
    uint4v u;
    u[0] = cvt_pk_bf16(f0[0], f0[1]);
    u[1] = cvt_pk_bf16(f0[2], f0[3]);
    u[2] = cvt_pk_bf16(f1[0], f1[1]);
    u[3] = cvt_pk_bf16(f1[2], f1[3]);
    return __builtin_bit_cast(short8, u);
}
static __device__ __forceinline__ float4v mfma_bf16(short8 a, short8 b, float4v c){
    return __builtin_amdgcn_mfma_f32_16x16x32_bf16(a, b, c, 0, 0, 0);
}
static __device__ __forceinline__ void barrier_lds(){
    asm volatile("s_waitcnt lgkmcnt(0)" ::: "memory");
    __builtin_amdgcn_s_barrier();
    asm volatile("" ::: "memory");
}

// ============ pre-pass 1: K (fp32) -> bf16, linear ============
__global__ void convert_k_kernel(const float* __restrict__ K,
                                 unsigned short* __restrict__ KW){
    size_t i = ((size_t)blockIdx.x * 256 + threadIdx.x) * 8;
    float4v a = *(const float4v*)(K + i);
    float4v b = *(const float4v*)(K + i + 4);
    uint4v u;
    u[0] = cvt_pk_bf16(a[0], a[1]);
    u[1] = cvt_pk_bf16(a[2], a[3]);
    u[2] = cvt_pk_bf16(b[0], b[1]);
    u[3] = cvt_pk_bf16(b[2], b[3]);
    *(uint4v*)(KW + i) = u;
}

// ============ pre-pass 2: V (fp32 [bh][kv][d]) -> V^T bf16 [bh][d][kv] ============
__global__ void transpose_v_kernel(const float* __restrict__ V,
                                   unsigned short* __restrict__ VTW){
    __shared__ unsigned short T[64][72];
    const int bid = blockIdx.x;
    const int bh  = bid >> 5;
    const int ct  = bid & 31;
    const int tid = threadIdx.x;

    const float* src = V + ((size_t)bh * NN + ct * 64) * DD;
    const int srow = tid >> 4;
    const int scol = (tid & 15) << 2;
    #pragma unroll
    for(int i = 0; i < 4; ++i){
        const int row = srow + 16 * i;
        float4v f = *(const float4v*)(src + (size_t)row * DD + scol);
        #pragma unroll
        for(int j = 0; j < 4; ++j)
            T[scol + j][row] = f2bf1(f[j]);
    }
    __syncthreads();
    unsigned short* dst = VTW + (size_t)bh * DD * NN + ct * 64;
    const int d  = tid >> 2;
    const int kc = (tid & 3) << 4;
    *(uint4v*)(dst + (size_t)d * NN + kc)     = *(const uint4v*)&T[d][kc];
    *(uint4v*)(dst + (size_t)d * NN + kc + 8) = *(const uint4v*)&T[d][kc + 8];
}

// ============ main: barrier-free fused attention ============
__launch_bounds__(256, 3)
__global__ void attn_main(const float* __restrict__ Q,
                          const float* __restrict__ Bias,
                          const unsigned short* __restrict__ KW,
                          const unsigned short* __restrict__ VTW,
                          float* __restrict__ Out){
    __shared__ uint32_t Pbh[4][16][LDH];     // per-wave P bounce (bf16 pairs)

    // XCD-aware decode: each XCD slot owns 2 whole heads; b-pair adjacent.
    const int raw  = blockIdx.x;
    const int slot = raw & 7;
    const int idx  = raw >> 3;
    const int b    = idx & 1;
    const int ghr  = slot * 64 + (idx >> 1);
    const int h    = ghr >> 5;
    const int rt   = ghr & 31;

    const int tid = threadIdx.x;
    const int l   = tid & 63;
    const int w   = tid >> 6;
    const int lg  = l >> 4;
    const int ll  = l & 15;
    const int vc  = ll * 4;

    const int qw = rt * 64 + w * 16;
    const size_t bh = (size_t)(b * HN + h);
    const float* Qg = Q + (bh * NN + qw) * DD;
    const unsigned short* kwF = KW  + bh * NN * DD + (size_t)ll * DD + lg * 8;
    const unsigned short* vtF = VTW + bh * DD * NN + (size_t)ll * NN + lg * 8;
    const float* BgA = Bias + (size_t)h * NN * NN + (size_t)(qw + lg * 4) * NN + ll;

    // Q fragments (A-frag: row=ll, k=ks*32+lg*8+j)
    short8 qf[2];
    {
        const float* qrow = Qg + (size_t)ll * DD + lg * 8;
        #pragma unroll
        for(int ks = 0; ks < 2; ++ks)
            qf[ks] = pack8(*(const float4v*)(qrow + ks * 32),
                           *(const float4v*)(qrow + ks * 32 + 4));
    }

    float lsum[4];
    #pragma unroll
    for(int r = 0; r < 4; ++r) lsum[r] = 0.f;

    // ====== PASS 1: barrier-free row sums; K frags direct from L2 (1-deep prefetch) ======
    short8 kf[8];
    float bb[16];
    #pragma unroll
    for(int sub = 0; sub < 4; ++sub){
        #pragma unroll
        for(int ks = 0; ks < 2; ++ks)
            kf[sub*2+ks] = __builtin_bit_cast(short8,
                *(const uint4v*)(kwF + (size_t)(sub*16) * DD + ks*32));
        #pragma unroll
        for(int r = 0; r < 4; ++r)
            bb[sub*4+r] = BgA[(size_t)r * NN + sub*16];
    }

    #pragma unroll 1
    for(int ct = 0; ct < NT; ++ct){
        short8 kn[8];
        float bn[16];
        if(ct + 1 < NT){
            const unsigned short* kp = kwF + (size_t)((ct+1)*KT) * DD;
            #pragma unroll
            for(int sub = 0; sub < 4; ++sub){
                #pragma unroll
                for(int ks = 0; ks < 2; ++ks)
                    kn[sub*2+ks] = __builtin_bit_cast(short8,
                        *(const uint4v*)(kp + (size_t)(sub*16) * DD + ks*32));
                #pragma unroll
                for(int r = 0; r < 4; ++r)
                    bn[sub*4+r] = BgA[(size_t)r * NN + (ct+1)*KT + sub*16];
            }
        }

        float4v acc[4];
        #pragma unroll
        for(int sub = 0; sub < 4; ++sub) acc[sub] = (float4v){0.f,0.f,0.f,0.f};
        __builtin_amdgcn_s_setprio(1);
        #pragma unroll
        for(int sub = 0; sub < 4; ++sub){
            acc[sub] = mfma_bf16(qf[0], kf[sub*2+0], acc[sub]);
            acc[sub] = mfma_bf16(qf[1], kf[sub*2+1], acc[sub]);
        }
        __builtin_amdgcn_s_setprio(0);

        #pragma unroll
        for(int r = 0; r < 4; ++r){
            float e0 = __expf(acc[0][r] * 0.125f + bb[r]);
            float e1 = __expf(acc[1][r] * 0.125f + bb[4+r]);
            float e2 = __expf(acc[2][r] * 0.125f + bb[8+r]);
            float e3 = __expf(acc[3][r] * 0.125f + bb[12+r]);
            lsum[r] += (e0 + e1) + (e2 + e3);
        }

        if(ct + 1 < NT){
            #pragma unroll
            for(int i = 0; i < 8; ++i)  kf[i] = kn[i];
            #pragma unroll
            for(int i = 0; i < 16; ++i) bb[i] = bn[i];
        }
    }

    float rl[4];
    #pragma unroll
    for(int r = 0; r < 4; ++r){
        #pragma unroll
        for(int d = 1; d < 16; d <<= 1) lsum[r] += __shfl_xor(lsum[r], d);
        rl[r] = 1.0f / lsum[r];
    }

    // ====== PASS 2: barrier-free; K + V^T frags direct from L2 ======
    float4v oacc[4];
    #pragma unroll
    for(int ds = 0; ds < 4; ++ds) oacc[ds] = (float4v){0.f,0.f,0.f,0.f};

    float* attnW = Out + (size_t)BN*HN*NN*DD
                 + (bh * NN + qw + lg) * (size_t)NN + vc;

    #pragma unroll 1
    for(int ct = 0; ct < NT; ++ct){
        // issue loads back-to-back: bias, K-frags, V-frags (all in flight together)
        float bb2[16];
        #pragma unroll
        for(int sub = 0; sub < 4; ++sub)
            #pragma unroll
            for(int r = 0; r < 4; ++r)
                bb2[sub*4+r] = BgA[(size_t)r * NN + ct*KT + sub*16];

        short8 kf2[8];
        {
            const unsigned short* kp = kwF + (size_t)(ct*KT) * DD;
            #pragma unroll
            for(int sub = 0; sub < 4; ++sub)
                #pragma unroll
                for(int ks = 0; ks < 2; ++ks)
                    kf2[sub*2+ks] = __builtin_bit_cast(short8,
                        *(const uint4v*)(kp + (size_t)(sub*16) * DD + ks*32));
        }
        short8 vf[8];
        #pragma unroll
        for(int ds = 0; ds < 4; ++ds)
            #pragma unroll
            for(int ks = 0; ks < 2; ++ks)
                vf[ds*2+ks] = __builtin_bit_cast(short8,
                    *(const uint4v*)(vtF + (size_t)(ds*16) * NN + ct*KT + ks*32));

        float4v acc[4];
        #pragma unroll
        for(int sub = 0; sub < 4; ++sub) acc[sub] = (float4v){0.f,0.f,0.f,0.f};
        __builtin_amdgcn_s_setprio(1);
        #pragma unroll
        for(int sub = 0; sub < 4; ++sub){
            acc[sub] = mfma_bf16(qf[0], kf2[sub*2+0], acc[sub]);
            acc[sub] = mfma_bf16(qf[1], kf2[sub*2+1], acc[sub]);
        }
        __builtin_amdgcn_s_setprio(0);

        // p = exp(s)*rl -> bf16 -> Pbh (acc layout)
        #pragma unroll
        for(int sub = 0; sub < 4; ++sub)
            #pragma unroll
            for(int r = 0; r < 4; ++r){
                float p = __expf(acc[sub][r] * 0.125f + bb2[sub*4+r]) * rl[r];
                ((unsigned short*)&Pbh[w][lg*4 + r][0])[sub*16 + ll] = f2bf1(p);
            }

        // wave-internal RAW on Pbh
        asm volatile("s_waitcnt lgkmcnt(0)" ::: "memory");

        short8 pf0 = __builtin_bit_cast(short8, *(const uint4v*)&Pbh[w][ll][lg*4]);
        short8 pf1 = __builtin_bit_cast(short8, *(const uint4v*)&Pbh[w][ll][16 + lg*4]);

        // attn store: vec-layout b64 reads -> fp32 -> dwordx4 stores
        #pragma unroll
        for(int it = 0; it < 4; ++it){
            uint2v pw = *(const uint2v*)&Pbh[w][lg + 4*it][ll*2];
            float4v pv;
            pv[0] = __builtin_bit_cast(float, pw[0] << 16);
            pv[1] = __builtin_bit_cast(float, pw[0] & 0xffff0000u);
            pv[2] = __builtin_bit_cast(float, pw[1] << 16);
            pv[3] = __builtin_bit_cast(float, pw[1] & 0xffff0000u);
            *(float4v*)(attnW + (size_t)(it*4) * NN + ct*KT) = pv;
        }

        // PV MFMA with direct V^T frags
        __builtin_amdgcn_s_setprio(1);
        #pragma unroll
        for(int ds = 0; ds < 4; ++ds){
            oacc[ds] = mfma_bf16(pf0, vf[ds*2+0], oacc[ds]);
            oacc[ds] = mfma_bf16(pf1, vf[ds*2+1], oacc[ds]);
        }
        __builtin_amdgcn_s_setprio(0);
    }

    float* outG = Out + (bh * NN + qw) * (size_t)DD;
    #pragma unroll
    for(int ds = 0; ds < 4; ++ds)
        #pragma unroll
        for(int r = 0; r < 4; ++r)
            outG[(size_t)(lg*4 + r) * DD + ds*16 + ll] = oacc[ds][r];
}

// ============ fallback: R8 kernel (used when ws is too small) ============
__launch_bounds__(256, 4)
__global__ void attn_fused_r8(const float* __restrict__ Q,
                              const float* __restrict__ K,
                              const float* __restrict__ V,
                              const float* __restrict__ Bias,
                              float* __restrict__ Out){
    __shared__ unsigned short Kb[KT][LDP];
    __shared__ unsigned short Vt[DD][LDP];
    __shared__ uint32_t Pbh[4][16][LDH];

    const int raw  = blockIdx.x;
    const int slot = raw & 7;
    const int idx  = raw >> 3;
    const int b    = idx & 1;
    const int ghr  = slot * 64 + (idx >> 1);
    const int h    = ghr >> 5;
    const int rt   = ghr & 31;

    const int tid = threadIdx.x;
    const int l   = tid & 63;
    const int w   = tid >> 6;
    const int lg  = l >> 4;
    const int ll  = l & 15;
    const int vc  = ll * 4;

    const int srow = tid >> 4;
    const int scol = (tid & 15) << 2;
    const int vsw  = ((tid >> 1) & 7) << 3;

    const int qw = rt * 64 + w * 16;
    const size_t bh = (size_t)(b * HN + h);
    const float* Qg = Q + (bh * NN + qw) * DD;
    const float* Kg = K + bh * NN * DD;
    const float* Vg = V + bh * NN * DD;
    const float* BgA = Bias + (size_t)h * NN * NN + (size_t)(qw + lg * 4) * NN + ll;

    short8 qf[2];
    {
        const float* qrow = Qg + (size_t)ll * DD + lg * 8;
        #pragma unroll
        for(int ks = 0; ks < 2; ++ks)
            qf[ks] = pack8(*(const float4v*)(qrow + ks * 32),
                           *(const float4v*)(qrow + ks * 32 + 4));
    }

    float lsum[4];
    #pragma unroll
    for(int r = 0; r < 4; ++r) lsum[r] = 0.f;

    float4v kreg[4];
    #pragma unroll
    for(int i = 0; i < 4; ++i)
        kreg[i] = *(const float4v*)(Kg + (size_t)(srow + 16*i) * DD + scol);

    for(int ct = 0; ct < NT; ++ct){
        barrier_lds();
        #pragma unroll
        for(int i = 0; i < 4; ++i){
            uint2v t = { cvt_pk_bf16(kreg[i][0], kreg[i][1]),
                         cvt_pk_bf16(kreg[i][2], kreg[i][3]) };
            *(uint2v*)&Kb[srow + 16*i][scol] = t;
        }
        float bb[16];
        #pragma unroll
        for(int sub = 0; sub < 4; ++sub)
            #pragma unroll
            for(int r = 0; r < 4; ++r)
                bb[sub*4+r] = BgA[(size_t)r * NN + ct*KT + sub*16];
        if(ct + 1 < NT){
            #pragma unroll
            for(int i = 0; i < 4; ++i)
                kreg[i] = *(const float4v*)(Kg + (size_t)((ct+1)*KT + srow + 16*i) * DD + scol);
        }
        barrier_lds();

        float4v acc[4];
        #pragma unroll
        for(int sub = 0; sub < 4; ++sub) acc[sub] = (float4v){0.f,0.f,0.f,0.f};
        __builtin_amdgcn_s_setprio(1);
        #pragma unroll
        for(int sub = 0; sub < 4; ++sub){
            short8 b0 = *(const short8*)&Kb[sub*16 + ll][lg*8];
            short8 b1 = *(const short8*)&Kb[sub*16 + ll][32 + lg*8];
            acc[sub] = mfma_bf16(qf[0], b0, acc[sub]);
            acc[sub] = mfma_bf16(qf[1], b1, acc[sub]);
        }
        __builtin_amdgcn_s_setprio(0);

        #pragma unroll
        for(int r = 0; r < 4; ++r){
            float e0 = __expf(acc[0][r] * 0.125f + bb[r]);
            float e1 = __expf(acc[1][r] * 0.125f + bb[4+r]);
            float e2 = __expf(acc[2][r] * 0.125f + bb[8+r]);
            float e3 = __expf(acc[3][r] * 0.125f + bb[12+r]);
            lsum[r] += (e0 + e1) + (e2 + e3);
        }
    }

    float rl[4];
    #pragma unroll
    for(int r = 0; r < 4; ++r){
        #pragma unroll
        for(int d = 1; d < 16; d <<= 1) lsum[r] += __shfl_xor(lsum[r], d);
        rl[r] = 1.0f / lsum[r];
    }

    float4v oacc[4];
    #pragma unroll
    for(int ds = 0; ds < 4; ++ds) oacc[ds] = (float4v){0.f,0.f,0.f,0.f};

    float* attnW = Out + (size_t)BN*HN*NN*DD
                 + (bh * NN + qw + lg) * (size_t)NN + vc;

    float4v vreg[4];
    #pragma unroll
    for(int i = 0; i < 4; ++i){
        kreg[i] = *(const float4v*)(Kg + (size_t)(srow + 16*i) * DD + scol);
        vreg[i] = *(const float4v*)(Vg + (size_t)(srow + 16*i) * DD + scol);
    }

    for(int ct = 0; ct < NT; ++ct){
        barrier_lds();
        #pragma unroll
        for(int i = 0; i < 4; ++i){
            uint2v t = { cvt_pk_bf16(kreg[i][0], kreg[i][1]),
                         cvt_pk_bf16(kreg[i][2], kreg[i][3]) };
            *(uint2v*)&Kb[srow + 16*i][scol] = t;
            #pragma unroll
            for(int j = 0; j < 4; ++j)
                Vt[scol + j][(srow + 16*i) ^ vsw] = f2bf1(vreg[i][j]);
        }
        float bb[16];
        #pragma unroll
        for(int sub = 0; sub < 4; ++sub)
            #pragma unroll
            for(int r = 0; r < 4; ++r)
                bb[sub*4+r] = BgA[(size_t)r * NN + ct*KT + sub*16];
        if(ct + 1 < NT){
            #pragma unroll
            for(int i = 0; i < 4; ++i){
                kreg[i] = *(const float4v*)(Kg + (size_t)((ct+1)*KT + srow + 16*i) * DD + scol);
                vreg[i] = *(const float4v*)(Vg + (size_t)((ct+1)*KT + srow + 16*i) * DD + scol);
            }
        }
        barrier_lds();

        float4v acc[4];
        #pragma unroll
        for(int sub = 0; sub < 4; ++sub) acc[sub] = (float4v){0.f,0.f,0.f,0.f};
        __builtin_amdgcn_s_setprio(1);
        #pragma unroll
        for(int sub = 0; sub < 4; ++sub){
            short8 b0 = *(const short8*)&Kb[sub*16 + ll][lg*8];
            short8 b1 = *(const short8*)&Kb[sub*16 + ll][32 + lg*8];
            acc[sub] = mfma_bf16(qf[0], b0, acc[sub]);
            acc[sub] = mfma_bf16(qf[1], b1, acc[sub]);
        }
        __builtin_amdgcn_s_setprio(0);

        #pragma unroll
        for(int sub = 0; sub < 4; ++sub)
            #pragma unroll
            for(int r = 0; r < 4; ++r){
                float p = __expf(acc[sub][r] * 0.125f + bb[sub*4+r]) * rl[r];
                ((unsigned short*)&Pbh[w][lg*4 + r][0])[sub*16 + ll] = f2bf1(p);
            }

        asm volatile("s_waitcnt lgkmcnt(0)" ::: "memory");

        short8 pf0 = __builtin_bit_cast(short8, *(const uint4v*)&Pbh[w][ll][lg*4]);
        short8 pf1 = __builtin_bit_cast(short8, *(const uint4v*)&Pbh[w][ll][16 + lg*4]);

        #pragma unroll
        for(int it = 0; it < 4; ++it){
            uint2v pw = *(const uint2v*)&Pbh[w][lg + 4*it][ll*2];
            float4v pv;
            pv[0] = __builtin_bit_cast(float, pw[0] << 16);
            pv[1] = __builtin_bit_cast(float, pw[0] & 0xffff0000u);
            pv[2] = __builtin_bit_cast(float, pw[1] << 16);
            pv[3] = __builtin_bit_cast(float, pw[1] & 0xffff0000u);
            *(float4v*)(attnW + (size_t)(it*4) * NN + ct*KT) = pv;
        }

        __builtin_amdgcn_s_setprio(1);
        #pragma unroll
        for(int ds = 0; ds < 4; ++ds){
            const int rsw = (2*ds + (ll >> 3)) << 3;
            short8 v0 = *(const short8*)&Vt[ds*16 + ll][(lg*8) ^ rsw];
            short8 v1 = *(const short8*)&Vt[ds*16 + ll][(32 + lg*8) ^ rsw];
            oacc[ds] = mfma_bf16(pf0, v0, oacc[ds]);
            oacc[ds] = mfma_bf16(pf1, v1, oacc[ds]);
        }
        __builtin_amdgcn_s_setprio(0);
    }

    float* outG = Out + (bh * NN + qw) * (size_t)DD;
    #pragma unroll
    for(int ds = 0; ds < 4; ++ds)
        #pragma unroll
        for(int r = 0; r < 4; ++r)
            outG[(size_t)(lg*4 + r) * DD + ds*16 + ll] = oacc[ds][r];
}

extern "C" void kernel_launch(void* const* d_in, const int* in_sizes, int n_in,
                              void* d_out, int out_size, void* d_ws, size_t ws_size,
                              hipStream_t stream) {
    const float* q    = (const float*)d_in[0];
    const float* k    = (const float*)d_in[1];
    const float* v    = (const float*)d_in[2];
    const float* bias = (const float*)d_in[3];
    float* out = (float*)d_out;

    const size_t need = 2 * KVELEMS * sizeof(unsigned short);   // 16.8 MB
    dim3 block(256);
    if(ws_size >= need){
        unsigned short* ws16 = (unsigned short*)d_ws;
        hipLaunchKernelGGL(convert_k_kernel, dim3(KVELEMS / 8 / 256), block, 0, stream,
                           k, ws16);
        hipLaunchKernelGGL(transpose_v_kernel, dim3(BN * HN * (NN / 64)), block, 0, stream,
                           v, ws16 + KVELEMS);
        hipLaunchKernelGGL(attn_main, dim3(BN * HN * (NN / 64)), block, 0, stream,
                           q, bias, ws16, ws16 + KVELEMS, out);
    } else {
        hipLaunchKernelGGL(attn_fused_r8, dim3(BN * HN * (NN / 64)), block, 0, stream,
                           q, k, v, bias, out);
    }
}

// Round 12
// 355.861 us; speedup vs baseline: 1.3775x; 1.3775x over previous
//
#include <hip/hip_runtime.h>
#include <cstdint>

#define BN 2
#define HN 16
#define NN 2048
#define DD 64
#define KT 64
#define NT (NN / KT)     // 32 tiles
#define LDP 72           // bf16 LDS row stride (Kb/Vt)
#define LDH 36           // u32 words per Pbh row (64 bf16 = 32 words + 4 pad)

typedef __attribute__((ext_vector_type(8))) short short8;
typedef __attribute__((ext_vector_type(2))) uint32_t uint2v;
typedef __attribute__((ext_vector_type(4))) uint32_t uint4v;
typedef __attribute__((ext_vector_type(4))) float float4v;

// packed f32->bf16 (RTNE), 2 elems / instr
static __device__ __forceinline__ uint32_t cvt_pk_bf16(float a, float b){
    uint32_t r;
    asm("v_cvt_pk_bf16_f32 %0, %1, %2" : "=v"(r) : "v"(a), "v"(b));
    return r;
}
static __device__ __forceinline__ unsigned short f2bf1(float a){
    return (unsigned short)(cvt_pk_bf16(a, a) & 0xffffu);
}
static __device__ __forceinline__ short8 pack8(float4v f0, float4v f1){
    uint4v u;
    u[0] = cvt_pk_bf16(f0[0], f0[1]);
    u[1] = cvt_pk_bf16(f0[2], f0[3]);
    u[2] = cvt_pk_bf16(f1[0], f1[1]);
    u[3] = cvt_pk_bf16(f1[2], f1[3]);
    return __builtin_bit_cast(short8, u);
}

static __device__ __forceinline__ float4v mfma_bf16(short8 a, short8 b, float4v c){
    return __builtin_amdgcn_mfma_f32_16x16x32_bf16(a, b, c, 0, 0, 0);
}

// Raw barrier: drain LDS ops only; global loads/stores stay in flight.
static __device__ __forceinline__ void barrier_lds(){
    asm volatile("s_waitcnt lgkmcnt(0)" ::: "memory");
    __builtin_amdgcn_s_barrier();
    asm volatile("" ::: "memory");
}

// NOTE: min-waves arg must stay 4. (256,5) forces VGPR 64->48 and spills
// (+960 MB scratch traffic, R9). Occupancy gain comes from LDS=27648 -> 5 blocks/CU.
__launch_bounds__(256, 4)
__global__ void attn_fused_kernel(const float* __restrict__ Q,
                                  const float* __restrict__ K,
                                  const float* __restrict__ V,
                                  const float* __restrict__ Bias,
                                  float* __restrict__ Out){
    __shared__ unsigned short Kb[KT][LDP];   // K tile [kv_row][d]
    __shared__ unsigned short Vt[DD][LDP];   // V^T tile [d][kv], kv XOR-swizzled
    __shared__ uint32_t Pbh[4][16][LDH];     // per-wave P bounce (bf16 pairs)

    // XCD-aware decode: each XCD slot owns 2 whole heads; b-pair adjacent.
    const int raw  = blockIdx.x;
    const int slot = raw & 7;
    const int idx  = raw >> 3;
    const int b    = idx & 1;
    const int ghr  = slot * 64 + (idx >> 1);   // (h,rt)
    const int h    = ghr >> 5;
    const int rt   = ghr & 31;

    const int tid = threadIdx.x;
    const int l   = tid & 63;
    const int w   = tid >> 6;
    const int lg  = l >> 4;           // acc-layout row group
    const int ll  = l & 15;           // acc-layout col
    const int vc  = ll * 4;           // vec-layout col

    // coalesced staging coords: wave instr = 4 rows x 256B
    const int srow = tid >> 4;        // 0..15 (+16*i)
    const int scol = (tid & 15) << 2; // element col
    const int vsw  = ((tid >> 1) & 7) << 3;   // Vt write swizzle

    const int qw = rt * 64 + w * 16;
    const size_t bh = (size_t)(b * HN + h);
    const float* Qg = Q + (bh * NN + qw) * DD;
    const float* Kg = K + bh * NN * DD;
    const float* Vg = V + bh * NN * DD;
    // acc-layout bias base: lane (lg,ll) reads row qw+lg*4+r, col sub*16+ll
    const float* BgA = Bias + (size_t)h * NN * NN + (size_t)(qw + lg * 4) * NN + ll;

    // ---- Q fragments (A-frag: row=ll, k=ks*32+lg*8+j) ----
    short8 qf[2];
    {
        const float* qrow = Qg + (size_t)ll * DD + lg * 8;
        #pragma unroll
        for(int ks = 0; ks < 2; ++ks)
            qf[ks] = pack8(*(const float4v*)(qrow + ks * 32),
                           *(const float4v*)(qrow + ks * 32 + 4));
    }

    float lsum[4];
    #pragma unroll
    for(int r = 0; r < 4; ++r) lsum[r] = 0.f;

    // =============== PASS 1: per-lane partial row sums ===============
    float4v kreg[4];
    #pragma unroll
    for(int i = 0; i < 4; ++i)
        kreg[i] = *(const float4v*)(Kg + (size_t)(srow + 16*i) * DD + scol);

    for(int ct = 0; ct < NT; ++ct){
        barrier_lds();                         // A
        #pragma unroll
        for(int i = 0; i < 4; ++i){            // stage K(t)
            uint2v t = { cvt_pk_bf16(kreg[i][0], kreg[i][1]),
                         cvt_pk_bf16(kreg[i][2], kreg[i][3]) };
            *(uint2v*)&Kb[srow + 16*i][scol] = t;
        }
        // bias(t) -> regs (acc layout, L2-resident); issued before K prefetch
        float bb[16];
        #pragma unroll
        for(int sub = 0; sub < 4; ++sub)
            #pragma unroll
            for(int r = 0; r < 4; ++r)
                bb[sub*4+r] = BgA[(size_t)r * NN + ct*KT + sub*16];
        if(ct + 1 < NT){                       // prefetch K(t+1)
            #pragma unroll
            for(int i = 0; i < 4; ++i)
                kreg[i] = *(const float4v*)(Kg + (size_t)((ct+1)*KT + srow + 16*i) * DD + scol);
        }
        barrier_lds();                         // B

        float4v acc[4];
        #pragma unroll
        for(int sub = 0; sub < 4; ++sub) acc[sub] = (float4v){0.f,0.f,0.f,0.f};
        __builtin_amdgcn_s_setprio(1);
        #pragma unroll
        for(int sub = 0; sub < 4; ++sub){
            short8 b0 = *(const short8*)&Kb[sub*16 + ll][lg*8];
            short8 b1 = *(const short8*)&Kb[sub*16 + ll][32 + lg*8];
            acc[sub] = mfma_bf16(qf[0], b0, acc[sub]);
            acc[sub] = mfma_bf16(qf[1], b1, acc[sub]);
        }
        __builtin_amdgcn_s_setprio(0);

        #pragma unroll
        for(int r = 0; r < 4; ++r){
            float e0 = __expf(acc[0][r] * 0.125f + bb[r]);
            float e1 = __expf(acc[1][r] * 0.125f + bb[4+r]);
            float e2 = __expf(acc[2][r] * 0.125f + bb[8+r]);
            float e3 = __expf(acc[3][r] * 0.125f + bb[12+r]);
            lsum[r] += (e0 + e1) + (e2 + e3);
        }
    }

    float rl[4];
    #pragma unroll
    for(int r = 0; r < 4; ++r){
        #pragma unroll
        for(int d = 1; d < 16; d <<= 1) lsum[r] += __shfl_xor(lsum[r], d);
        rl[r] = 1.0f / lsum[r];
    }

    // =============== PASS 2: attn stores + O = P*V ===============
    float4v oacc[4];
    #pragma unroll
    for(int ds = 0; ds < 4; ++ds) oacc[ds] = (float4v){0.f,0.f,0.f,0.f};

    float* attnW = Out + (size_t)BN*HN*NN*DD
                 + (bh * NN + qw + lg) * (size_t)NN + vc;

    float4v vreg[4];
    #pragma unroll
    for(int i = 0; i < 4; ++i){
        kreg[i] = *(const float4v*)(Kg + (size_t)(srow + 16*i) * DD + scol);
        vreg[i] = *(const float4v*)(Vg + (size_t)(srow + 16*i) * DD + scol);
    }

    for(int ct = 0; ct < NT; ++ct){
        barrier_lds();                         // A
        #pragma unroll
        for(int i = 0; i < 4; ++i){            // stage K(t) + V^T(t) swizzled
            uint2v t = { cvt_pk_bf16(kreg[i][0], kreg[i][1]),
                         cvt_pk_bf16(kreg[i][2], kreg[i][3]) };
            *(uint2v*)&Kb[srow + 16*i][scol] = t;
            #pragma unroll
            for(int j = 0; j < 4; ++j)
                Vt[scol + j][(srow + 16*i) ^ vsw] = f2bf1(vreg[i][j]);
        }
        float bb[16];
        #pragma unroll
        for(int sub = 0; sub < 4; ++sub)
            #pragma unroll
            for(int r = 0; r < 4; ++r)
                bb[sub*4+r] = BgA[(size_t)r * NN + ct*KT + sub*16];
        if(ct + 1 < NT){                       // prefetch K/V(t+1)
            #pragma unroll
            for(int i = 0; i < 4; ++i){
                kreg[i] = *(const float4v*)(Kg + (size_t)((ct+1)*KT + srow + 16*i) * DD + scol);
                vreg[i] = *(const float4v*)(Vg + (size_t)((ct+1)*KT + srow + 16*i) * DD + scol);
            }
        }
        barrier_lds();                         // B

        float4v acc[4];
        #pragma unroll
        for(int sub = 0; sub < 4; ++sub) acc[sub] = (float4v){0.f,0.f,0.f,0.f};
        __builtin_amdgcn_s_setprio(1);
        #pragma unroll
        for(int sub = 0; sub < 4; ++sub){
            short8 b0 = *(const short8*)&Kb[sub*16 + ll][lg*8];
            short8 b1 = *(const short8*)&Kb[sub*16 + ll][32 + lg*8];
            acc[sub] = mfma_bf16(qf[0], b0, acc[sub]);
            acc[sub] = mfma_bf16(qf[1], b1, acc[sub]);
        }
        __builtin_amdgcn_s_setprio(0);

        // p = exp(s)*rl -> bf16 -> Pbh (acc layout, b16 stores)
        #pragma unroll
        for(int sub = 0; sub < 4; ++sub)
            #pragma unroll
            for(int r = 0; r < 4; ++r){
                float p = __expf(acc[sub][r] * 0.125f + bb[sub*4+r]) * rl[r];
                ((unsigned short*)&Pbh[w][lg*4 + r][0])[sub*16 + ll] = f2bf1(p);
            }

        // wave-internal RAW on Pbh
        asm volatile("s_waitcnt lgkmcnt(0)" ::: "memory");

        // PV A-frags: direct bf16 b128 reads (no cvt)
        short8 pf0 = __builtin_bit_cast(short8, *(const uint4v*)&Pbh[w][ll][lg*4]);
        short8 pf1 = __builtin_bit_cast(short8, *(const uint4v*)&Pbh[w][ll][16 + lg*4]);

        // attn store: vec-layout b64 reads -> fp32 -> dwordx4 stores
        #pragma unroll
        for(int it = 0; it < 4; ++it){
            uint2v pw = *(const uint2v*)&Pbh[w][lg + 4*it][ll*2];
            float4v pv;
            pv[0] = __builtin_bit_cast(float, pw[0] << 16);
            pv[1] = __builtin_bit_cast(float, pw[0] & 0xffff0000u);
            pv[2] = __builtin_bit_cast(float, pw[1] << 16);
            pv[3] = __builtin_bit_cast(float, pw[1] & 0xffff0000u);
            *(float4v*)(attnW + (size_t)(it*4) * NN + ct*KT) = pv;
        }

        // PV MFMA: B-frags from swizzled Vt
        __builtin_amdgcn_s_setprio(1);
        #pragma unroll
        for(int ds = 0; ds < 4; ++ds){
            const int rsw = (2*ds + (ll >> 3)) << 3;
            short8 v0 = *(const short8*)&Vt[ds*16 + ll][(lg*8) ^ rsw];
            short8 v1 = *(const short8*)&Vt[ds*16 + ll][(32 + lg*8) ^ rsw];
            oacc[ds] = mfma_bf16(pf0, v0, oacc[ds]);
            oacc[ds] = mfma_bf16(pf1, v1, oacc[ds]);
        }
        __builtin_amdgcn_s_setprio(0);
    }

    // O store
    float* outG = Out + (bh * NN + qw) * (size_t)DD;
    #pragma unroll
    for(int ds = 0; ds < 4; ++ds)
        #pragma unroll
        for(int r = 0; r < 4; ++r)
            outG[(size_t)(lg*4 + r) * DD + ds*16 + ll] = oacc[ds][r];
}

extern "C" void kernel_launch(void* const* d_in, const int* in_sizes, int n_in,
                              void* d_out, int out_size, void* d_ws, size_t ws_size,
                              hipStream_t stream) {
    const float* q    = (const float*)d_in[0];
    const float* k    = (const float*)d_in[1];
    const float* v    = (const float*)d_in[2];
    const float* bias = (const float*)d_in[3];
    float* out = (float*)d_out;

    dim3 grid(BN * HN * (NN / 64));
    dim3 block(256);
    hipLaunchKernelGGL(attn_fused_kernel, grid, block, 0, stream, q, k, v, bias, out);
}

// Round 13
// 350.023 us; speedup vs baseline: 1.4005x; 1.0167x over previous
//
#include <hip/hip_runtime.h>
#include <cstdint>

#define BN 2
#define HN 16
#define NN 2048
#define DD 64
#define KT 64
#define NT (NN / KT)     // 32 tiles
#define LDP 72           // bf16 LDS row stride (Kb/Vt)
#define LDF 68           // fp32 LDS row stride (Pb)

typedef __attribute__((ext_vector_type(8))) short short8;
typedef __attribute__((ext_vector_type(2))) uint32_t uint2v;
typedef __attribute__((ext_vector_type(4))) uint32_t uint4v;
typedef __attribute__((ext_vector_type(4))) float float4v;

// packed f32->bf16 (RTNE), 2 elems / instr
static __device__ __forceinline__ uint32_t cvt_pk_bf16(float a, float b){
    uint32_t r;
    asm("v_cvt_pk_bf16_f32 %0, %1, %2" : "=v"(r) : "v"(a), "v"(b));
    return r;
}
static __device__ __forceinline__ unsigned short f2bf1(float a){
    return (unsigned short)(cvt_pk_bf16(a, a) & 0xffffu);
}
static __device__ __forceinline__ short8 pack8(float4v f0, float4v f1){
    uint4v u;
    u[0] = cvt_pk_bf16(f0[0], f0[1]);
    u[1] = cvt_pk_bf16(f0[2], f0[3]);
    u[2] = cvt_pk_bf16(f1[0], f1[1]);
    u[3] = cvt_pk_bf16(f1[2], f1[3]);
    return __builtin_bit_cast(short8, u);
}

static __device__ __forceinline__ float4v mfma_bf16(short8 a, short8 b, float4v c){
    return __builtin_amdgcn_mfma_f32_16x16x32_bf16(a, b, c, 0, 0, 0);
}

// Raw barrier: drain LDS ops only; global loads/stores stay in flight.
static __device__ __forceinline__ void barrier_lds(){
    asm volatile("s_waitcnt lgkmcnt(0)" ::: "memory");
    __builtin_amdgcn_s_barrier();
    asm volatile("" ::: "memory");
}
static __device__ __forceinline__ void lgkm_drain(){
    asm volatile("s_waitcnt lgkmcnt(0)" ::: "memory");
}

// NOTE: min-waves must stay 4 — (256,5) forced VGPR 48 and spilled (+960 MB, R9).
__launch_bounds__(256, 4)
__global__ void attn_fused_kernel(const float* __restrict__ Q,
                                  const float* __restrict__ K,
                                  const float* __restrict__ V,
                                  const float* __restrict__ Bias,
                                  float* __restrict__ Out){
    __shared__ unsigned short Kb[KT][LDP];   // K tile [kv_row][d]
    __shared__ unsigned short Vt[DD][LDP];   // V^T tile [d][kv], kv XOR-swizzled
    __shared__ float Pb[4][16][LDF];         // per-wave S/P bounce (fp32, wave-private)

    // XCD-aware decode: each XCD slot owns 2 whole heads; b-pair adjacent.
    const int raw  = blockIdx.x;
    const int slot = raw & 7;
    const int idx  = raw >> 3;
    const int b    = idx & 1;
    const int ghr  = slot * 64 + (idx >> 1);   // (h,rt)
    const int h    = ghr >> 5;
    const int rt   = ghr & 31;

    const int tid = threadIdx.x;
    const int l   = tid & 63;
    const int w   = tid >> 6;
    const int lg  = l >> 4;           // acc-layout row group
    const int ll  = l & 15;           // acc-layout col
    const int vc  = ll * 4;           // vec-layout col

    // coalesced staging coords: wave instr = 4 rows x 256B
    const int srow = tid >> 4;        // 0..15 (+16*i)
    const int scol = (tid & 15) << 2; // element col
    const int vsw  = ((tid >> 1) & 7) << 3;   // Vt write swizzle

    const int qw = rt * 64 + w * 16;
    const size_t bh = (size_t)(b * HN + h);
    const float* Qg = Q + (bh * NN + qw) * DD;
    const float* Kg = K + bh * NN * DD;
    const float* Vg = V + bh * NN * DD;
    // vec-layout bias base: lane covers rows qw+lg+4*it, cols vc..vc+3
    const float* BgV = Bias + (size_t)h * NN * NN + (size_t)(qw + lg) * NN + vc;

    // ---- Q fragments (A-frag: row=ll, k=ks*32+lg*8+j) ----
    short8 qf[2];
    {
        const float* qrow = Qg + (size_t)ll * DD + lg * 8;
        #pragma unroll
        for(int ks = 0; ks < 2; ++ks)
            qf[ks] = pack8(*(const float4v*)(qrow + ks * 32),
                           *(const float4v*)(qrow + ks * 32 + 4));
    }

    // vec-layout row sums: lsumv[it] = partial sum for q-row qw+lg+4*it
    float lsumv[4];
    #pragma unroll
    for(int it = 0; it < 4; ++it) lsumv[it] = 0.f;

    // =============== PASS 1: row sums via S-bounce (bias stays in vec regs) ===============
    float4v kreg[4];
    #pragma unroll
    for(int i = 0; i < 4; ++i)
        kreg[i] = *(const float4v*)(Kg + (size_t)(srow + 16*i) * DD + scol);

    for(int ct = 0; ct < NT; ++ct){
        barrier_lds();                         // A
        // bias(t) vec loads: issue early, consumed after MFMA+bounce
        float4v bv[4];
        #pragma unroll
        for(int it = 0; it < 4; ++it)
            bv[it] = *(const float4v*)(BgV + (size_t)(it * 4) * NN + ct*KT);
        #pragma unroll
        for(int i = 0; i < 4; ++i){            // stage K(t)
            uint2v t = { cvt_pk_bf16(kreg[i][0], kreg[i][1]),
                         cvt_pk_bf16(kreg[i][2], kreg[i][3]) };
            *(uint2v*)&Kb[srow + 16*i][scol] = t;
        }
        if(ct + 1 < NT){                       // prefetch K(t+1)
            #pragma unroll
            for(int i = 0; i < 4; ++i)
                kreg[i] = *(const float4v*)(Kg + (size_t)((ct+1)*KT + srow + 16*i) * DD + scol);
        }
        barrier_lds();                         // B

        float4v acc[4];
        #pragma unroll
        for(int sub = 0; sub < 4; ++sub) acc[sub] = (float4v){0.f,0.f,0.f,0.f};
        __builtin_amdgcn_s_setprio(1);
        #pragma unroll
        for(int sub = 0; sub < 4; ++sub){
            short8 b0 = *(const short8*)&Kb[sub*16 + ll][lg*8];
            short8 b1 = *(const short8*)&Kb[sub*16 + ll][32 + lg*8];
            acc[sub] = mfma_bf16(qf[0], b0, acc[sub]);
            acc[sub] = mfma_bf16(qf[1], b1, acc[sub]);
        }
        __builtin_amdgcn_s_setprio(0);

        // S bounce: acc layout -> Pb (scaled)
        #pragma unroll
        for(int sub = 0; sub < 4; ++sub)
            #pragma unroll
            for(int r = 0; r < 4; ++r)
                Pb[w][lg*4 + r][sub*16 + ll] = acc[sub][r] * 0.125f;
        lgkm_drain();

        // vec-layout read + bias + exp + accumulate
        #pragma unroll
        for(int it = 0; it < 4; ++it){
            float4v sv = *(const float4v*)&Pb[w][it*4 + lg][vc];
            lsumv[it] += (__expf(sv[0] + bv[it][0]) + __expf(sv[1] + bv[it][1]))
                       + (__expf(sv[2] + bv[it][2]) + __expf(sv[3] + bv[it][3]));
        }
    }

    // reduce over the 16 ll-lanes (cols); result already in the vec layout pass 2 uses
    float rlv[4];
    #pragma unroll
    for(int it = 0; it < 4; ++it){
        #pragma unroll
        for(int d = 1; d < 16; d <<= 1) lsumv[it] += __shfl_xor(lsumv[it], d);
        rlv[it] = 1.0f / lsumv[it];
    }

    // =============== PASS 2: S-bounce, attn stores from regs, O = P*V ===============
    float4v oacc[4];
    #pragma unroll
    for(int ds = 0; ds < 4; ++ds) oacc[ds] = (float4v){0.f,0.f,0.f,0.f};

    float* attnW = Out + (size_t)BN*HN*NN*DD
                 + (bh * NN + qw + lg) * (size_t)NN + vc;

    float4v vreg[4];
    #pragma unroll
    for(int i = 0; i < 4; ++i){
        kreg[i] = *(const float4v*)(Kg + (size_t)(srow + 16*i) * DD + scol);
        vreg[i] = *(const float4v*)(Vg + (size_t)(srow + 16*i) * DD + scol);
    }

    for(int ct = 0; ct < NT; ++ct){
        barrier_lds();                         // A
        float4v bv[4];
        #pragma unroll
        for(int it = 0; it < 4; ++it)
            bv[it] = *(const float4v*)(BgV + (size_t)(it * 4) * NN + ct*KT);
        #pragma unroll
        for(int i = 0; i < 4; ++i){            // stage K(t) + V^T(t) swizzled
            uint2v t = { cvt_pk_bf16(kreg[i][0], kreg[i][1]),
                         cvt_pk_bf16(kreg[i][2], kreg[i][3]) };
            *(uint2v*)&Kb[srow + 16*i][scol] = t;
            #pragma unroll
            for(int j = 0; j < 4; ++j)
                Vt[scol + j][(srow + 16*i) ^ vsw] = f2bf1(vreg[i][j]);
        }
        if(ct + 1 < NT){                       // prefetch K/V(t+1)
            #pragma unroll
            for(int i = 0; i < 4; ++i){
                kreg[i] = *(const float4v*)(Kg + (size_t)((ct+1)*KT + srow + 16*i) * DD + scol);
                vreg[i] = *(const float4v*)(Vg + (size_t)((ct+1)*KT + srow + 16*i) * DD + scol);
            }
        }
        barrier_lds();                         // B

        float4v acc[4];
        #pragma unroll
        for(int sub = 0; sub < 4; ++sub) acc[sub] = (float4v){0.f,0.f,0.f,0.f};
        __builtin_amdgcn_s_setprio(1);
        #pragma unroll
        for(int sub = 0; sub < 4; ++sub){
            short8 b0 = *(const short8*)&Kb[sub*16 + ll][lg*8];
            short8 b1 = *(const short8*)&Kb[sub*16 + ll][32 + lg*8];
            acc[sub] = mfma_bf16(qf[0], b0, acc[sub]);
            acc[sub] = mfma_bf16(qf[1], b1, acc[sub]);
        }
        __builtin_amdgcn_s_setprio(0);

        // S bounce: acc -> Pb (scaled)
        #pragma unroll
        for(int sub = 0; sub < 4; ++sub)
            #pragma unroll
            for(int r = 0; r < 4; ++r)
                Pb[w][lg*4 + r][sub*16 + ll] = acc[sub][r] * 0.125f;
        lgkm_drain();

        // vec layout: p = exp(S+bias)*rlv -> attn store (straight from regs) + p back to Pb
        // (per-it row sets are disjoint: reads of it touch rows 4it..4it+3, writes of it'<it
        //  touch rows <4it; in-order wave DS pipe keeps same-it read before write)
        #pragma unroll
        for(int it = 0; it < 4; ++it){
            float4v sv = *(const float4v*)&Pb[w][it*4 + lg][vc];
            float4v p;
            p[0] = __expf(sv[0] + bv[it][0]) * rlv[it];
            p[1] = __expf(sv[1] + bv[it][1]) * rlv[it];
            p[2] = __expf(sv[2] + bv[it][2]) * rlv[it];
            p[3] = __expf(sv[3] + bv[it][3]) * rlv[it];
            *(float4v*)(attnW + (size_t)(it*4) * NN + ct*KT) = p;
            *(float4v*)&Pb[w][it*4 + lg][vc] = p;
        }
        lgkm_drain();

        // PV A-frags from Pb rows ll (fp32 -> bf16 via cvt_pk)
        short8 pf0, pf1;
        {
            float4v p0 = *(const float4v*)&Pb[w][ll][lg*8];
            float4v p1 = *(const float4v*)&Pb[w][ll][lg*8 + 4];
            float4v p2 = *(const float4v*)&Pb[w][ll][32 + lg*8];
            float4v p3 = *(const float4v*)&Pb[w][ll][32 + lg*8 + 4];
            pf0 = pack8(p0, p1);
            pf1 = pack8(p2, p3);
        }

        // PV MFMA: B-frags from swizzled Vt
        __builtin_amdgcn_s_setprio(1);
        #pragma unroll
        for(int ds = 0; ds < 4; ++ds){
            const int rsw = (2*ds + (ll >> 3)) << 3;
            short8 v0 = *(const short8*)&Vt[ds*16 + ll][(lg*8) ^ rsw];
            short8 v1 = *(const short8*)&Vt[ds*16 + ll][(32 + lg*8) ^ rsw];
            oacc[ds] = mfma_bf16(pf0, v0, oacc[ds]);
            oacc[ds] = mfma_bf16(pf1, v1, oacc[ds]);
        }
        __builtin_amdgcn_s_setprio(0);
    }

    // O store
    float* outG = Out + (bh * NN + qw) * (size_t)DD;
    #pragma unroll
    for(int ds = 0; ds < 4; ++ds)
        #pragma unroll
        for(int r = 0; r < 4; ++r)
            outG[(size_t)(lg*4 + r) * DD + ds*16 + ll] = oacc[ds][r];
}

extern "C" void kernel_launch(void* const* d_in, const int* in_sizes, int n_in,
                              void* d_out, int out_size, void* d_ws, size_t ws_size,
                              hipStream_t stream) {
    const float* q    = (const float*)d_in[0];
    const float* k    = (const float*)d_in[1];
    const float* v    = (const float*)d_in[2];
    const float* bias = (const float*)d_in[3];
    float* out = (float*)d_out;

    dim3 grid(BN * HN * (NN / 64));
    dim3 block(256);
    hipLaunchKernelGGL(attn_fused_kernel, grid, block, 0, stream, q, k, v, bias, out);
}

// Round 14
// 290.765 us; speedup vs baseline: 1.6859x; 1.2038x over previous
//
#include <hip/hip_runtime.h>
#include <cstdint>

#define BN 2
#define HN 16
#define NN 2048
#define DD 64
#define KT 64
#define NT (NN / KT)     // 32 tiles
#define QB 128           // q-rows per block (8 waves x 16)
#define LDP 72           // bf16 LDS row stride (Kb/Vt)
#define LDF 68           // fp32 LDS row stride (Pb) — stride%32==4 keeps scalar reads 2-way

typedef __attribute__((ext_vector_type(8))) short short8;
typedef __attribute__((ext_vector_type(2))) uint32_t uint2v;
typedef __attribute__((ext_vector_type(4))) uint32_t uint4v;
typedef __attribute__((ext_vector_type(4))) float float4v;

// packed f32->bf16 (RTNE), 2 elems / instr
static __device__ __forceinline__ uint32_t cvt_pk_bf16(float a, float b){
    uint32_t r;
    asm("v_cvt_pk_bf16_f32 %0, %1, %2" : "=v"(r) : "v"(a), "v"(b));
    return r;
}
static __device__ __forceinline__ unsigned short f2bf1(float a){
    return (unsigned short)(cvt_pk_bf16(a, a) & 0xffffu);
}
static __device__ __forceinline__ short8 pack8(float4v f0, float4v f1){
    uint4v u;
    u[0] = cvt_pk_bf16(f0[0], f0[1]);
    u[1] = cvt_pk_bf16(f0[2], f0[3]);
    u[2] = cvt_pk_bf16(f1[0], f1[1]);
    u[3] = cvt_pk_bf16(f1[2], f1[3]);
    return __builtin_bit_cast(short8, u);
}

static __device__ __forceinline__ float4v mfma_bf16(short8 a, short8 b, float4v c){
    return __builtin_amdgcn_mfma_f32_16x16x32_bf16(a, b, c, 0, 0, 0);
}

// Raw barrier: drain LDS ops only; global loads/stores stay in flight.
static __device__ __forceinline__ void barrier_lds(){
    asm volatile("s_waitcnt lgkmcnt(0)" ::: "memory");
    __builtin_amdgcn_s_barrier();
    asm volatile("" ::: "memory");
}

// 512 threads, 2 blocks/CU target -> VGPR cap 128 (do NOT raise: R9 spill lesson).
__launch_bounds__(512, 4)
__global__ void attn_fused_kernel(const float* __restrict__ Q,
                                  const float* __restrict__ K,
                                  const float* __restrict__ V,
                                  const float* __restrict__ Bias,
                                  float* __restrict__ Out){
    __shared__ unsigned short Kb[2][KT][LDP];   // double-buffered K tile [kv][d]
    __shared__ unsigned short Vt[2][DD][LDP];   // double-buffered V^T tile, kv XOR-swizzled
    __shared__ float Pb[8][16][LDF];            // per-wave bias/P bounce (fp32, wave-private)

    // XCD-aware decode: 512 blocks, slot raw&7 owns 2 whole heads (bias/K/V L2-resident).
    const int raw  = blockIdx.x;
    const int slot = raw & 7;
    const int idx  = raw >> 3;            // 0..63
    const int h    = slot * 2 + (idx >> 5);
    const int rem  = idx & 31;
    const int b    = rem & 1;             // batch pair adjacent -> shares bias slice
    const int rt   = rem >> 1;            // 0..15

    const int tid = threadIdx.x;
    const int l   = tid & 63;
    const int w   = tid >> 6;             // wave 0..7
    const int lg  = l >> 4;               // acc-layout row group
    const int ll  = l & 15;               // acc-layout col
    const int vc  = ll * 4;               // vec-layout col

    // staging coords: 512 threads cover 64x64 tile in 2 row-batches (wave instr = 4 rows x 256B)
    const int srow = tid >> 4;            // 0..31 (+32*i)
    const int scol = (tid & 15) << 2;     // element col
    const int vsw  = ((tid >> 1) & 7) << 3;   // Vt write swizzle = fn(d>>3)

    const int qw = rt * QB + w * 16;
    const size_t bh = (size_t)(b * HN + h);
    const float* Qg = Q + (bh * NN + qw) * DD;
    const float* Kg = K + bh * NN * DD;
    const float* Vg = V + bh * NN * DD;
    // vec-layout bias base: lane covers rows qw+lg+4*it, cols vc..vc+3
    const float* BgV = Bias + (size_t)h * NN * NN + (size_t)(qw + lg) * NN + vc;

    // ---- Q fragments (A-frag: row=ll, k=ks*32+lg*8+j) ----
    short8 qf[2];
    {
        const float* qrow = Qg + (size_t)ll * DD + lg * 8;
        #pragma unroll
        for(int ks = 0; ks < 2; ++ks)
            qf[ks] = pack8(*(const float4v*)(qrow + ks * 32),
                           *(const float4v*)(qrow + ks * 32 + 4));
    }

    float lsum[4];
    #pragma unroll
    for(int r = 0; r < 4; ++r) lsum[r] = 0.f;

    // =============== PASS 1: row sums; Kb double-buffered, 1 barrier/tile ===============
    float4v kreg[2], bv[4];
    #pragma unroll
    for(int i = 0; i < 2; ++i)
        kreg[i] = *(const float4v*)(Kg + (size_t)(srow + 32*i) * DD + scol);
    #pragma unroll
    for(int i = 0; i < 2; ++i){            // stage tile 0 -> buf 0
        uint2v t = { cvt_pk_bf16(kreg[i][0], kreg[i][1]),
                     cvt_pk_bf16(kreg[i][2], kreg[i][3]) };
        *(uint2v*)&Kb[0][srow + 32*i][scol] = t;
    }
    #pragma unroll
    for(int i = 0; i < 2; ++i)             // load tile 1
        kreg[i] = *(const float4v*)(Kg + (size_t)(KT + srow + 32*i) * DD + scol);
    #pragma unroll
    for(int it = 0; it < 4; ++it)
        bv[it] = *(const float4v*)(BgV + (size_t)(it * 4) * NN);
    barrier_lds();

    for(int ct = 0; ct < NT; ++ct){
        const int cur = ct & 1;
        if(ct + 1 < NT){                   // stage t+1 into other buffer (full-tile slack)
            #pragma unroll
            for(int i = 0; i < 2; ++i){
                uint2v t = { cvt_pk_bf16(kreg[i][0], kreg[i][1]),
                             cvt_pk_bf16(kreg[i][2], kreg[i][3]) };
                *(uint2v*)&Kb[cur ^ 1][srow + 32*i][scol] = t;
            }
        }
        if(ct + 2 < NT){                   // load t+2
            #pragma unroll
            for(int i = 0; i < 2; ++i)
                kreg[i] = *(const float4v*)(Kg + (size_t)((ct+2)*KT + srow + 32*i) * DD + scol);
        }
        #pragma unroll
        for(int it = 0; it < 4; ++it)      // stage bias(t) (Pb wave-private, no barrier)
            *(float4v*)&Pb[w][it*4 + lg][vc] = bv[it];
        if(ct + 1 < NT){
            #pragma unroll
            for(int it = 0; it < 4; ++it)
                bv[it] = *(const float4v*)(BgV + (size_t)(it * 4) * NN + (ct+1)*KT);
        }

        float4v acc[4];
        #pragma unroll
        for(int sub = 0; sub < 4; ++sub) acc[sub] = (float4v){0.f,0.f,0.f,0.f};
        __builtin_amdgcn_s_setprio(1);
        #pragma unroll
        for(int sub = 0; sub < 4; ++sub){
            short8 b0 = *(const short8*)&Kb[cur][sub*16 + ll][lg*8];
            short8 b1 = *(const short8*)&Kb[cur][sub*16 + ll][32 + lg*8];
            acc[sub] = mfma_bf16(qf[0], b0, acc[sub]);
            acc[sub] = mfma_bf16(qf[1], b1, acc[sub]);
        }
        __builtin_amdgcn_s_setprio(0);

        #pragma unroll
        for(int r = 0; r < 4; ++r){
            float e0 = __expf(acc[0][r] * 0.125f + Pb[w][lg*4+r][      ll]);
            float e1 = __expf(acc[1][r] * 0.125f + Pb[w][lg*4+r][16 +  ll]);
            float e2 = __expf(acc[2][r] * 0.125f + Pb[w][lg*4+r][32 +  ll]);
            float e3 = __expf(acc[3][r] * 0.125f + Pb[w][lg*4+r][48 +  ll]);
            lsum[r] += (e0 + e1) + (e2 + e3);
        }
        barrier_lds();                     // single barrier: publishes buf[cur^1]
    }

    float rl[4];
    #pragma unroll
    for(int r = 0; r < 4; ++r){
        #pragma unroll
        for(int d = 1; d < 16; d <<= 1) lsum[r] += __shfl_xor(lsum[r], d);
        rl[r] = 1.0f / lsum[r];
    }

    // =============== PASS 2: attn stores + O = P*V; Kb/Vt dbuf, 1 barrier/tile ===============
    float4v oacc[4];
    #pragma unroll
    for(int ds = 0; ds < 4; ++ds) oacc[ds] = (float4v){0.f,0.f,0.f,0.f};

    float* attnW = Out + (size_t)BN*HN*NN*DD
                 + (bh * NN + qw + lg) * (size_t)NN + vc;

    float4v vreg[2];
    #pragma unroll
    for(int i = 0; i < 2; ++i){
        kreg[i] = *(const float4v*)(Kg + (size_t)(srow + 32*i) * DD + scol);
        vreg[i] = *(const float4v*)(Vg + (size_t)(srow + 32*i) * DD + scol);
    }
    #pragma unroll
    for(int i = 0; i < 2; ++i){            // stage tile 0 -> buf 0
        uint2v t = { cvt_pk_bf16(kreg[i][0], kreg[i][1]),
                     cvt_pk_bf16(kreg[i][2], kreg[i][3]) };
        *(uint2v*)&Kb[0][srow + 32*i][scol] = t;
        #pragma unroll
        for(int j = 0; j < 4; ++j)
            Vt[0][scol + j][(srow + 32*i) ^ vsw] = f2bf1(vreg[i][j]);
    }
    #pragma unroll
    for(int i = 0; i < 2; ++i){            // load tile 1
        kreg[i] = *(const float4v*)(Kg + (size_t)(KT + srow + 32*i) * DD + scol);
        vreg[i] = *(const float4v*)(Vg + (size_t)(KT + srow + 32*i) * DD + scol);
    }
    #pragma unroll
    for(int it = 0; it < 4; ++it)
        bv[it] = *(const float4v*)(BgV + (size_t)(it * 4) * NN);
    barrier_lds();

    for(int ct = 0; ct < NT; ++ct){
        const int cur = ct & 1;
        if(ct + 1 < NT){                   // stage t+1 (K + V^T swizzled)
            #pragma unroll
            for(int i = 0; i < 2; ++i){
                uint2v t = { cvt_pk_bf16(kreg[i][0], kreg[i][1]),
                             cvt_pk_bf16(kreg[i][2], kreg[i][3]) };
                *(uint2v*)&Kb[cur ^ 1][srow + 32*i][scol] = t;
                #pragma unroll
                for(int j = 0; j < 4; ++j)
                    Vt[cur ^ 1][scol + j][(srow + 32*i) ^ vsw] = f2bf1(vreg[i][j]);
            }
        }
        if(ct + 2 < NT){                   // load t+2
            #pragma unroll
            for(int i = 0; i < 2; ++i){
                kreg[i] = *(const float4v*)(Kg + (size_t)((ct+2)*KT + srow + 32*i) * DD + scol);
                vreg[i] = *(const float4v*)(Vg + (size_t)((ct+2)*KT + srow + 32*i) * DD + scol);
            }
        }
        #pragma unroll
        for(int it = 0; it < 4; ++it)      // stage bias(t) (wave-private)
            *(float4v*)&Pb[w][it*4 + lg][vc] = bv[it];
        if(ct + 1 < NT){
            #pragma unroll
            for(int it = 0; it < 4; ++it)
                bv[it] = *(const float4v*)(BgV + (size_t)(it * 4) * NN + (ct+1)*KT);
        }

        float4v acc[4];
        #pragma unroll
        for(int sub = 0; sub < 4; ++sub) acc[sub] = (float4v){0.f,0.f,0.f,0.f};
        __builtin_amdgcn_s_setprio(1);
        #pragma unroll
        for(int sub = 0; sub < 4; ++sub){
            short8 b0 = *(const short8*)&Kb[cur][sub*16 + ll][lg*8];
            short8 b1 = *(const short8*)&Kb[cur][sub*16 + ll][32 + lg*8];
            acc[sub] = mfma_bf16(qf[0], b0, acc[sub]);
            acc[sub] = mfma_bf16(qf[1], b1, acc[sub]);
        }
        __builtin_amdgcn_s_setprio(0);

        // p = exp(s)*rl; overwrite bias slot in Pb (same element, same lane)
        #pragma unroll
        for(int sub = 0; sub < 4; ++sub)
            #pragma unroll
            for(int r = 0; r < 4; ++r){
                float sv = acc[sub][r] * 0.125f + Pb[w][lg*4+r][sub*16+ll];
                Pb[w][lg*4+r][sub*16+ll] = __expf(sv) * rl[r];
            }

        // PV A-frags from Pb rows ll (fp32 -> bf16 via cvt_pk)
        short8 pf0, pf1;
        {
            float4v p0 = *(const float4v*)&Pb[w][ll][lg*8];
            float4v p1 = *(const float4v*)&Pb[w][ll][lg*8 + 4];
            float4v p2 = *(const float4v*)&Pb[w][ll][32 + lg*8];
            float4v p3 = *(const float4v*)&Pb[w][ll][32 + lg*8 + 4];
            pf0 = pack8(p0, p1);
            pf1 = pack8(p2, p3);
        }

        // vectorized attn store: 4 x dwordx4/thread (stays in flight across raw barriers)
        #pragma unroll
        for(int it = 0; it < 4; ++it){
            float4v pv = *(const float4v*)&Pb[w][it*4 + lg][vc];
            *(float4v*)(attnW + (size_t)(it*4) * NN + ct*KT) = pv;
        }

        // PV MFMA: B-frags from swizzled Vt[cur]
        __builtin_amdgcn_s_setprio(1);
        #pragma unroll
        for(int ds = 0; ds < 4; ++ds){
            const int rsw = (2*ds + (ll >> 3)) << 3;
            short8 v0 = *(const short8*)&Vt[cur][ds*16 + ll][(lg*8) ^ rsw];
            short8 v1 = *(const short8*)&Vt[cur][ds*16 + ll][(32 + lg*8) ^ rsw];
            oacc[ds] = mfma_bf16(pf0, v0, oacc[ds]);
            oacc[ds] = mfma_bf16(pf1, v1, oacc[ds]);
        }
        __builtin_amdgcn_s_setprio(0);

        barrier_lds();                     // single barrier: publishes buf[cur^1]
    }

    // O store
    float* outG = Out + (bh * NN + qw) * (size_t)DD;
    #pragma unroll
    for(int ds = 0; ds < 4; ++ds)
        #pragma unroll
        for(int r = 0; r < 4; ++r)
            outG[(size_t)(lg*4 + r) * DD + ds*16 + ll] = oacc[ds][r];
}

extern "C" void kernel_launch(void* const* d_in, const int* in_sizes, int n_in,
                              void* d_out, int out_size, void* d_ws, size_t ws_size,
                              hipStream_t stream) {
    const float* q    = (const float*)d_in[0];
    const float* k    = (const float*)d_in[1];
    const float* v    = (const float*)d_in[2];
    const float* bias = (const float*)d_in[3];
    float* out = (float*)d_out;

    dim3 grid(BN * HN * (NN / QB));   // 512 blocks, 2 per CU
    dim3 block(512);
    hipLaunchKernelGGL(attn_fused_kernel, grid, block, 0, stream, q, k, v, bias, out);
}

// Round 15
// 287.430 us; speedup vs baseline: 1.7055x; 1.0116x over previous
//
#include <hip/hip_runtime.h>
#include <cstdint>

#define BN 2
#define HN 16
#define NN 2048
#define DD 64
#define KT 64
#define NT (NN / KT)     // 32 tiles
#define QB 128           // q-rows per block (8 waves x 16)
#define LDP 72           // bf16 LDS row stride (Kb/Vt)
#define LDF 68           // fp32 LDS row stride (Pb)

typedef __attribute__((ext_vector_type(8))) short short8;
typedef __attribute__((ext_vector_type(2))) uint32_t uint2v;
typedef __attribute__((ext_vector_type(4))) uint32_t uint4v;
typedef __attribute__((ext_vector_type(4))) float float4v;

// packed f32->bf16 (RTNE), 2 elems / instr
static __device__ __forceinline__ uint32_t cvt_pk_bf16(float a, float b){
    uint32_t r;
    asm("v_cvt_pk_bf16_f32 %0, %1, %2" : "=v"(r) : "v"(a), "v"(b));
    return r;
}
static __device__ __forceinline__ unsigned short f2bf1(float a){
    return (unsigned short)(cvt_pk_bf16(a, a) & 0xffffu);
}
static __device__ __forceinline__ short8 pack8(float4v f0, float4v f1){
    uint4v u;
    u[0] = cvt_pk_bf16(f0[0], f0[1]);
    u[1] = cvt_pk_bf16(f0[2], f0[3]);
    u[2] = cvt_pk_bf16(f1[0], f1[1]);
    u[3] = cvt_pk_bf16(f1[2], f1[3]);
    return __builtin_bit_cast(short8, u);
}

static __device__ __forceinline__ float4v mfma_bf16(short8 a, short8 b, float4v c){
    return __builtin_amdgcn_mfma_f32_16x16x32_bf16(a, b, c, 0, 0, 0);
}

// Raw barrier: drain LDS ops only; global loads/stores stay in flight.
static __device__ __forceinline__ void barrier_lds(){
    asm volatile("s_waitcnt lgkmcnt(0)" ::: "memory");
    __builtin_amdgcn_s_barrier();
    asm volatile("" ::: "memory");
}
static __device__ __forceinline__ void lgkm_drain(){
    asm volatile("s_waitcnt lgkmcnt(0)" ::: "memory");
}

// 512 threads, 2 blocks/CU. VGPR cap 128 (R9 lesson: never force below natural).
__launch_bounds__(512, 4)
__global__ void attn_fused_kernel(const float* __restrict__ Q,
                                  const float* __restrict__ K,
                                  const float* __restrict__ V,
                                  const float* __restrict__ Bias,
                                  float* __restrict__ Out){
    __shared__ unsigned short Kb[2][KT][LDP];   // double-buffered K tile [kv][d]
    __shared__ unsigned short Vt[2][DD][LDP];   // double-buffered V^T tile, kv XOR-swizzled
    __shared__ float Pb[8][16][LDF];            // per-wave bias/P bounce (fp32, wave-private)

    // XCD-aware decode: slot raw&7 owns 2 whole heads (bias/K/V L2-resident).
    const int raw  = blockIdx.x;
    const int slot = raw & 7;
    const int idx  = raw >> 3;            // 0..63
    const int h    = slot * 2 + (idx >> 5);
    const int rem  = idx & 31;
    const int b    = rem & 1;             // batch pair adjacent -> shares bias slice
    const int rt   = rem >> 1;            // 0..15

    const int tid = threadIdx.x;
    const int l   = tid & 63;
    const int w   = tid >> 6;             // wave 0..7
    const int lg  = l >> 4;               // acc-layout row group
    const int ll  = l & 15;               // acc-layout col
    const int vc  = ll * 4;               // vec-layout col

    // staging coords: wave instr = 4 rows x 256B
    const int srow = tid >> 4;            // 0..31 (+32*i)
    const int scol = (tid & 15) << 2;     // element col
    const int vsw  = ((tid >> 1) & 7) << 3;   // Vt write swizzle

    const int qw = rt * QB + w * 16;
    const size_t bh = (size_t)(b * HN + h);
    const float* Qg = Q + (bh * NN + qw) * DD;
    const float* Kg = K + bh * NN * DD;
    const float* Vg = V + bh * NN * DD;
    // vec-layout bias base: lane covers rows qw+lg+4*it, cols vc..vc+3
    const float* BgV = Bias + (size_t)h * NN * NN + (size_t)(qw + lg) * NN + vc;

    // ---- Q fragments (A-frag: row=ll, k=ks*32+lg*8+j) ----
    short8 qf[2];
    {
        const float* qrow = Qg + (size_t)ll * DD + lg * 8;
        #pragma unroll
        for(int ks = 0; ks < 2; ++ks)
            qf[ks] = pack8(*(const float4v*)(qrow + ks * 32),
                           *(const float4v*)(qrow + ks * 32 + 4));
    }

    float lsum[4];
    #pragma unroll
    for(int r = 0; r < 4; ++r) lsum[r] = 0.f;

    // =============== PASS 1: row sums; Kb double-buffered, 1 barrier/tile ===============
    float4v kreg[2], bv[4];
    #pragma unroll
    for(int i = 0; i < 2; ++i)
        kreg[i] = *(const float4v*)(Kg + (size_t)(srow + 32*i) * DD + scol);
    #pragma unroll
    for(int i = 0; i < 2; ++i){            // stage tile 0 -> buf 0
        uint2v t = { cvt_pk_bf16(kreg[i][0], kreg[i][1]),
                     cvt_pk_bf16(kreg[i][2], kreg[i][3]) };
        *(uint2v*)&Kb[0][srow + 32*i][scol] = t;
    }
    #pragma unroll
    for(int i = 0; i < 2; ++i)             // load tile 1
        kreg[i] = *(const float4v*)(Kg + (size_t)(KT + srow + 32*i) * DD + scol);
    #pragma unroll
    for(int it = 0; it < 4; ++it)
        bv[it] = *(const float4v*)(BgV + (size_t)(it * 4) * NN);
    barrier_lds();

    for(int ct = 0; ct < NT; ++ct){
        const int cur = ct & 1;
        if(ct + 1 < NT){                   // stage t+1 into other buffer
            #pragma unroll
            for(int i = 0; i < 2; ++i){
                uint2v t = { cvt_pk_bf16(kreg[i][0], kreg[i][1]),
                             cvt_pk_bf16(kreg[i][2], kreg[i][3]) };
                *(uint2v*)&Kb[cur ^ 1][srow + 32*i][scol] = t;
            }
        }
        if(ct + 2 < NT){                   // load t+2
            #pragma unroll
            for(int i = 0; i < 2; ++i)
                kreg[i] = *(const float4v*)(Kg + (size_t)((ct+2)*KT + srow + 32*i) * DD + scol);
        }
        #pragma unroll
        for(int it = 0; it < 4; ++it)      // stage bias(t) (Pb wave-private)
            *(float4v*)&Pb[w][it*4 + lg][vc] = bv[it];
        if(ct + 1 < NT){
            #pragma unroll
            for(int it = 0; it < 4; ++it)
                bv[it] = *(const float4v*)(BgV + (size_t)(it * 4) * NN + (ct+1)*KT);
        }

        float4v acc[4];
        #pragma unroll
        for(int sub = 0; sub < 4; ++sub) acc[sub] = (float4v){0.f,0.f,0.f,0.f};
        __builtin_amdgcn_s_setprio(1);
        #pragma unroll
        for(int sub = 0; sub < 4; ++sub){
            short8 b0 = *(const short8*)&Kb[cur][sub*16 + ll][lg*8];
            short8 b1 = *(const short8*)&Kb[cur][sub*16 + ll][32 + lg*8];
            acc[sub] = mfma_bf16(qf[0], b0, acc[sub]);
            acc[sub] = mfma_bf16(qf[1], b1, acc[sub]);
        }
        __builtin_amdgcn_s_setprio(0);

        #pragma unroll
        for(int r = 0; r < 4; ++r){
            float e0 = __expf(acc[0][r] * 0.125f + Pb[w][lg*4+r][      ll]);
            float e1 = __expf(acc[1][r] * 0.125f + Pb[w][lg*4+r][16 +  ll]);
            float e2 = __expf(acc[2][r] * 0.125f + Pb[w][lg*4+r][32 +  ll]);
            float e3 = __expf(acc[3][r] * 0.125f + Pb[w][lg*4+r][48 +  ll]);
            lsum[r] += (e0 + e1) + (e2 + e3);
        }
        barrier_lds();                     // publishes buf[cur^1]
    }

    float rl[4];
    #pragma unroll
    for(int r = 0; r < 4; ++r){
        #pragma unroll
        for(int d = 1; d < 16; d <<= 1) lsum[r] += __shfl_xor(lsum[r], d);
        rl[r] = 1.0f / lsum[r];
    }

    // =============== PASS 2: pipelined softmax/PV; Kb/Vt dbuf, 1 barrier/tile ===============
    float4v oacc[4];
    #pragma unroll
    for(int ds = 0; ds < 4; ++ds) oacc[ds] = (float4v){0.f,0.f,0.f,0.f};

    float* attnW = Out + (size_t)BN*HN*NN*DD
                 + (bh * NN + qw + lg) * (size_t)NN + vc;

    float4v vreg[2];
    #pragma unroll
    for(int i = 0; i < 2; ++i){
        kreg[i] = *(const float4v*)(Kg + (size_t)(srow + 32*i) * DD + scol);
        vreg[i] = *(const float4v*)(Vg + (size_t)(srow + 32*i) * DD + scol);
    }
    #pragma unroll
    for(int i = 0; i < 2; ++i){            // stage tile 0 -> buf 0
        uint2v t = { cvt_pk_bf16(kreg[i][0], kreg[i][1]),
                     cvt_pk_bf16(kreg[i][2], kreg[i][3]) };
        *(uint2v*)&Kb[0][srow + 32*i][scol] = t;
        #pragma unroll
        for(int j = 0; j < 4; ++j)
            Vt[0][scol + j][(srow + 32*i) ^ vsw] = f2bf1(vreg[i][j]);
    }
    #pragma unroll
    for(int i = 0; i < 2; ++i){            // load tile 1
        kreg[i] = *(const float4v*)(Kg + (size_t)(KT + srow + 32*i) * DD + scol);
        vreg[i] = *(const float4v*)(Vg + (size_t)(KT + srow + 32*i) * DD + scol);
    }
    #pragma unroll
    for(int it = 0; it < 4; ++it)
        bv[it] = *(const float4v*)(BgV + (size_t)(it * 4) * NN);
    barrier_lds();

    for(int ct = 0; ct < NT; ++ct){
        const int cur = ct & 1;
        if(ct + 1 < NT){                   // stage t+1 (K + V^T swizzled)
            #pragma unroll
            for(int i = 0; i < 2; ++i){
                uint2v t = { cvt_pk_bf16(kreg[i][0], kreg[i][1]),
                             cvt_pk_bf16(kreg[i][2], kreg[i][3]) };
                *(uint2v*)&Kb[cur ^ 1][srow + 32*i][scol] = t;
                #pragma unroll
                for(int j = 0; j < 4; ++j)
                    Vt[cur ^ 1][scol + j][(srow + 32*i) ^ vsw] = f2bf1(vreg[i][j]);
            }
        }
        if(ct + 2 < NT){                   // load t+2
            #pragma unroll
            for(int i = 0; i < 2; ++i){
                kreg[i] = *(const float4v*)(Kg + (size_t)((ct+2)*KT + srow + 32*i) * DD + scol);
                vreg[i] = *(const float4v*)(Vg + (size_t)((ct+2)*KT + srow + 32*i) * DD + scol);
            }
        }
        #pragma unroll
        for(int it = 0; it < 4; ++it)      // stage bias(t) (wave-private)
            *(float4v*)&Pb[w][it*4 + lg][vc] = bv[it];
        if(ct + 1 < NT){
            #pragma unroll
            for(int it = 0; it < 4; ++it)
                bv[it] = *(const float4v*)(BgV + (size_t)(it * 4) * NN + (ct+1)*KT);
        }

        float4v acc[4];
        #pragma unroll
        for(int sub = 0; sub < 4; ++sub) acc[sub] = (float4v){0.f,0.f,0.f,0.f};
        __builtin_amdgcn_s_setprio(1);
        #pragma unroll
        for(int sub = 0; sub < 4; ++sub){
            short8 b0 = *(const short8*)&Kb[cur][sub*16 + ll][lg*8];
            short8 b1 = *(const short8*)&Kb[cur][sub*16 + ll][32 + lg*8];
            acc[sub] = mfma_bf16(qf[0], b0, acc[sub]);
            acc[sub] = mfma_bf16(qf[1], b1, acc[sub]);
        }
        __builtin_amdgcn_s_setprio(0);

        // ---- K-half pipelined softmax/PV bridge ----
        // p for subs 0,1 (cols 0..31): read bias, exp, overwrite Pb slot
        #pragma unroll
        for(int sub = 0; sub < 2; ++sub)
            #pragma unroll
            for(int r = 0; r < 4; ++r){
                float sv = acc[sub][r] * 0.125f + Pb[w][lg*4+r][sub*16+ll];
                Pb[w][lg*4+r][sub*16+ll] = __expf(sv) * rl[r];
            }
        lgkm_drain();

        // pf0 (cols 0..31) ready
        short8 pf0;
        {
            float4v p0 = *(const float4v*)&Pb[w][ll][lg*8];
            float4v p1 = *(const float4v*)&Pb[w][ll][lg*8 + 4];
            pf0 = pack8(p0, p1);
        }
        // p for subs 2,3 (cols 32..63) — overlaps with PV kb=0 below
        #pragma unroll
        for(int sub = 2; sub < 4; ++sub)
            #pragma unroll
            for(int r = 0; r < 4; ++r){
                float sv = acc[sub][r] * 0.125f + Pb[w][lg*4+r][sub*16+ll];
                Pb[w][lg*4+r][sub*16+ll] = __expf(sv) * rl[r];
            }

        // PV kb=0 while subs 2,3 softmax retires
        __builtin_amdgcn_s_setprio(1);
        #pragma unroll
        for(int ds = 0; ds < 4; ++ds){
            const int rsw = (2*ds + (ll >> 3)) << 3;
            short8 v0 = *(const short8*)&Vt[cur][ds*16 + ll][(lg*8) ^ rsw];
            oacc[ds] = mfma_bf16(pf0, v0, oacc[ds]);
        }
        __builtin_amdgcn_s_setprio(0);
        lgkm_drain();

        // pf1 (cols 32..63) ready
        short8 pf1;
        {
            float4v p2 = *(const float4v*)&Pb[w][ll][32 + lg*8];
            float4v p3 = *(const float4v*)&Pb[w][ll][32 + lg*8 + 4];
            pf1 = pack8(p2, p3);
        }
        __builtin_amdgcn_s_setprio(1);
        #pragma unroll
        for(int ds = 0; ds < 4; ++ds){
            const int rsw = (2*ds + (ll >> 3)) << 3;
            short8 v1 = *(const short8*)&Vt[cur][ds*16 + ll][(32 + lg*8) ^ rsw];
            oacc[ds] = mfma_bf16(pf1, v1, oacc[ds]);
        }
        __builtin_amdgcn_s_setprio(0);

        // attn store last: all 64 cols of Pb hold p (drained above)
        #pragma unroll
        for(int it = 0; it < 4; ++it){
            float4v pv = *(const float4v*)&Pb[w][it*4 + lg][vc];
            *(float4v*)(attnW + (size_t)(it*4) * NN + ct*KT) = pv;
        }

        barrier_lds();                     // publishes buf[cur^1]
    }

    // O store
    float* outG = Out + (bh * NN + qw) * (size_t)DD;
    #pragma unroll
    for(int ds = 0; ds < 4; ++ds)
        #pragma unroll
        for(int r = 0; r < 4; ++r)
            outG[(size_t)(lg*4 + r) * DD + ds*16 + ll] = oacc[ds][r];
}

extern "C" void kernel_launch(void* const* d_in, const int* in_sizes, int n_in,
                              void* d_out, int out_size, void* d_ws, size_t ws_size,
                              hipStream_t stream) {
    const float* q    = (const float*)d_in[0];
    const float* k    = (const float*)d_in[1];
    const float* v    = (const float*)d_in[2];
    const float* bias = (const float*)d_in[3];
    float* out = (float*)d_out;

    dim3 grid(BN * HN * (NN / QB));   // 512 blocks, 2 per CU
    dim3 block(512);
    hipLaunchKernelGGL(attn_fused_kernel, grid, block, 0, stream, q, k, v, bias, out);
}